// Round 7
// baseline (1273.474 us; speedup 1.0000x reference)
//
#include <hip/hip_runtime.h>

#define NN 131072
#define NE 2097152

typedef unsigned short u16;
typedef unsigned int u32;
typedef __attribute__((ext_vector_type(8))) short bf16x8;
typedef __attribute__((ext_vector_type(4))) float f32x4;
typedef __attribute__((ext_vector_type(2))) float f32x2;

__device__ __forceinline__ float bf2f(u16 v) {
  unsigned u = ((unsigned)v) << 16;
  return __builtin_bit_cast(float, u);
}
__device__ __forceinline__ float blo(u32 v) {
  return __builtin_bit_cast(float, v << 16);
}
__device__ __forceinline__ float bhi(u32 v) {
  return __builtin_bit_cast(float, v & 0xffff0000u);
}
__device__ __forceinline__ u16 f2bf(float f) {
  unsigned u = __builtin_bit_cast(unsigned, f);
  unsigned r = (u + 0x7fffu + ((u >> 16) & 1u)) >> 16;
  return (u16)r;
}

#define WDQ 3.0518509475997192e-05f  // 1/32767

// ---------------- workspace layout (bytes) ----------------
// F12 (fp8 z1/z2 pair-interleaved [node][256]) = 32 MB, exactly the H16
// region (dead after conv GEMMs; N*256 == 33554432). F3 (fp8 z3, [node][128])
// = first 16 MB of the Z region. re (u16 edge ranks) = second half of Z
// (dead before F3 written). Stage-2 fp8 buffer FS2 overlays H16 (F12 dead
// after agg3_press). P (bf16 press output) overlays A.
#define H16_OFF 0ull               // bf16 [N,128] 32 MB / later F12 fp8 [N,256]
#define A_OFF 33554432ull          // bf16 [N,128] 32 MB
#define B_OFF 67108864ull          // bf16
#define C_OFF 100663296ull         // bf16
#define Z_OFF 134217728ull         // 32 MB (first 16 MB = F3 fp8; re in 2nd half)
#define RE_OFF 150994944ull        // u16 [E] edge ranks
#define CSR_OFF 167772160ull       // E x u32 packed {src:17, w:15} = 8 MB
#define RP_OFF 184549376ull        // N+1 ints (reserve 528384)
#define DEG_OFF 185077760ull       // N ints
#define BS_OFF 186126336ull        // 512 ints (reserve 4096)
#define SUMS_OFF 186130432ull      // [4][2][128] f32
#define HG_OFF 186134528ull        // [16][384] f32
#define WT16_OFF 186159104ull      // conv w: 3 conv x 3 tap x 128 x 136 u16
#define WP16_OFF 186472448ull      // 6 mats x 128 x 136 u16
#define CP_OFF 186681344ull        // 4 x 128 f32
#define SV_OFF 186683392ull        // 4 x 128 f32
#define SHV_OFF 186685440ull       // 4 x 128 f32

// ---------------- zero-init (graph-capture safe) ----------------
__global__ void zerok(int* __restrict__ deg, float* __restrict__ sums,
                      float* __restrict__ hg) {
  int i = blockIdx.x * 256 + threadIdx.x;  // 512*256 = 131072
  deg[i] = 0;
  if (i < 1024) sums[i] = 0.f;
  if (i < 6144) hg[i] = 0.f;
}

// ---- h (f32) -> H16 (bf16), fused with per-edge deg count + rank ----
// grid 8192*256 = 2097152 threads == NE: thread i converts 8 h-elems AND
// processes edge i's deg atomic (atomic latency hides the streaming copy).
__global__ void h2bf_deg(const float* __restrict__ h, u16* __restrict__ o,
                         const int* __restrict__ dst, int* __restrict__ deg,
                         u16* __restrict__ re) {
  int i = blockIdx.x * 256 + threadIdx.x;  // x8 elements; also edge id
  float4 v0 = *(const float4*)(h + (size_t)i * 8);
  float4 v1 = *(const float4*)(h + (size_t)i * 8 + 4);
  ushort4 a, b;
  a.x = f2bf(v0.x); a.y = f2bf(v0.y); a.z = f2bf(v0.z); a.w = f2bf(v0.w);
  b.x = f2bf(v1.x); b.y = f2bf(v1.y); b.z = f2bf(v1.z); b.w = f2bf(v1.w);
  *(ushort4*)(o + (size_t)i * 8) = a;
  *(ushort4*)(o + (size_t)i * 8 + 4) = b;
  int d = dst[i];
  int r = atomicAdd(&deg[d], 1);
  re[i] = (u16)r;
}

// ---- conv weights -> bf16 transposed padded: [conv][tap][o=128][ipad=136] ----
__global__ void prep_wT16(const float* __restrict__ w1, const float* __restrict__ w2,
                          const float* __restrict__ w3, u16* __restrict__ wT) {
  int e = blockIdx.x * 256 + threadIdx.x;
  if (e >= 3 * 3 * 128 * 128) return;
  int o = e & 127;
  int i = (e >> 7) & 127;
  int ct = e >> 14;
  int t = ct % 3, c = ct / 3;
  const float* w = (c == 0) ? w1 : (c == 1) ? w2 : w3;
  wT[(size_t)(c * 3 + t) * 17408 + o * 136 + i] = f2bf(w[(o * 128 + i) * 3 + t]);
}

// ---- gemm weights -> bf16 transposed padded [o=128][ipad=136], opt. BN fold ----
__global__ void wprep16(const float* __restrict__ W, const float* __restrict__ sv,
                        u16* __restrict__ Wt) {
  int e = blockIdx.x * 256 + threadIdx.x;  // 16384
  int o = e & 127, i = e >> 7;
  float s = sv ? sv[i] : 1.f;
  Wt[o * 136 + i] = f2bf(s * W[i * 128 + o]);
}

__global__ void cprep(const float* __restrict__ W, const float* __restrict__ shv,
                      float* __restrict__ cp) {
  int j = threadIdx.x;
  float a = 0.f;
  for (int i = 0; i < 128; ++i) a += shv[i] * W[i * 128 + j];
  cp[j] = a;
}

// ---------------- BN params ----------------
__global__ void bnparam(const float* __restrict__ sums, const float* __restrict__ g,
                        const float* __restrict__ b, float* __restrict__ sv,
                        float* __restrict__ shv, int tensor0) {
  int t = tensor0 + blockIdx.x;
  int o = threadIdx.x;
  float mu = sums[t * 256 + o] / (float)NN;
  float var = sums[t * 256 + 128 + o] / (float)NN - mu * mu;
  float s = g[o] * rsqrtf(var + 1e-5f);
  sv[t * 128 + o] = s;
  shv[t * 128 + o] = b[o] - mu * s;
}

// ---------------- MFMA GEMM: z[n,:] = sum_t x[n+shift_t,:] @ W_t ----------------
// OUT8=1: output written as fp8 e4m3 bytes at node stride zsb (128 or 256)
template <int TAPS, int DIL, int OUT8>
__global__ __launch_bounds__(256, 4) void mfma_gemm(const u16* __restrict__ x,
                                                    const u16* __restrict__ wt,
                                                    u16* __restrict__ z, int zsb) {
  __shared__ u16 sh[17408];
  int tid = threadIdx.x;
  int lane = tid & 63, wave = tid >> 6;
  int n0 = blockIdx.x * 128;
  int m = lane & 15, quad = lane >> 4;
  int koff = quad * 8;
  f32x4 acc[2][8];
#pragma unroll
  for (int a = 0; a < 2; ++a)
#pragma unroll
    for (int b = 0; b < 8; ++b) acc[a][b] = (f32x4){0.f, 0.f, 0.f, 0.f};
  int rbase = n0 + wave * 32 + m;

  for (int t = 0; t < TAPS; ++t) {
    if (TAPS > 1) __syncthreads();
    for (int idx = tid; idx < 2176; idx += 256)
      ((uint4*)sh)[idx] = ((const uint4*)(wt + (size_t)t * 17408))[idx];
    __syncthreads();
    const int shift = (TAPS == 3) ? (t - 1) * DIL : 0;
#pragma unroll
    for (int ks = 0; ks < 4; ++ks) {
      bf16x8 af[2];
#pragma unroll
      for (int rt = 0; rt < 2; ++rt) {
        int row = rbase + rt * 16 + shift;
        if (TAPS == 3) {
          int rc = min(max(row, 0), NN - 1);
          bf16x8 v = *(const bf16x8*)(x + (size_t)rc * 128 + ks * 32 + koff);
          bf16x8 zz = {};
          af[rt] = (row >= 0 && row < NN) ? v : zz;
        } else {
          af[rt] = *(const bf16x8*)(x + (size_t)row * 128 + ks * 32 + koff);
        }
      }
#pragma unroll
      for (int ct = 0; ct < 8; ++ct) {
        bf16x8 bf = *(const bf16x8*)(sh + (ct * 16 + m) * 136 + ks * 32 + koff);
        acc[0][ct] =
            __builtin_amdgcn_mfma_f32_16x16x32_bf16(af[0], bf, acc[0][ct], 0, 0, 0);
        acc[1][ct] =
            __builtin_amdgcn_mfma_f32_16x16x32_bf16(af[1], bf, acc[1][ct], 0, 0, 0);
      }
    }
  }
  __syncthreads();
#pragma unroll
  for (int rt = 0; rt < 2; ++rt)
#pragma unroll
    for (int ct = 0; ct < 8; ++ct)
#pragma unroll
      for (int r = 0; r < 4; ++r) {
        int rowl = wave * 32 + rt * 16 + quad * 4 + r;
        sh[rowl * 136 + ct * 16 + m] = f2bf(acc[rt][ct][r]);
      }
  __syncthreads();
  if (OUT8) {
    unsigned char* z8 = (unsigned char*)z;
#pragma unroll
    for (int it = 0; it < 8; ++it) {
      int q = tid + it * 256;
      int row = q >> 4, g = q & 15;
      uint4 v = *(const uint4*)(sh + row * 136 + g * 8);
      int w0 = __builtin_amdgcn_cvt_pk_fp8_f32(blo(v.x), bhi(v.x), 0, false);
      w0 = __builtin_amdgcn_cvt_pk_fp8_f32(blo(v.y), bhi(v.y), w0, true);
      int w1 = __builtin_amdgcn_cvt_pk_fp8_f32(blo(v.z), bhi(v.z), 0, false);
      w1 = __builtin_amdgcn_cvt_pk_fp8_f32(blo(v.w), bhi(v.w), w1, true);
      uint2 st;
      st.x = (u32)w0;
      st.y = (u32)w1;
      *(uint2*)(z8 + (size_t)(n0 + row) * zsb + g * 8) = st;
    }
  } else {
#pragma unroll
    for (int it = 0; it < 8; ++it) {
      int q = tid + it * 256;
      int row = q >> 4, g = q & 15;
      uint4 v = *(const uint4*)(sh + row * 136 + g * 8);
      *(uint4*)(z + (size_t)(n0 + row) * 128 + g * 8) = v;
    }
  }
}

// ------- combine: t1=relu(c1)+c2, t2=relu(c2)+c3, t3=relu(c3)+c1 (bf16 in-place) ---
__global__ __launch_bounds__(256) void combine(u16* __restrict__ A, u16* __restrict__ B,
                                               u16* __restrict__ C,
                                               const float* __restrict__ b1,
                                               const float* __restrict__ b2,
                                               const float* __restrict__ b3,
                                               float* __restrict__ sums) {
  __shared__ float red[2 * 128 * 6];
  int tid = threadIdx.x;
  int o = tid & 127, half = tid >> 7;
  int n0 = blockIdx.x * 32 + half * 16;
  float bb1 = b1[o], bb2 = b2[o], bb3 = b3[o];
  float s1 = 0, q1 = 0, s2 = 0, q2 = 0, s3 = 0, q3 = 0;
  for (int j = 0; j < 16; ++j) {
    size_t idx = (size_t)(n0 + j) * 128 + o;
    float c1 = bf2f(A[idx]) + bb1, c2 = bf2f(B[idx]) + bb2, c3 = bf2f(C[idx]) + bb3;
    float v1 = fmaxf(c1, 0.f) + c2;
    float v2 = fmaxf(c2, 0.f) + c3;
    float v3 = fmaxf(c3, 0.f) + c1;
    A[idx] = f2bf(v1);
    B[idx] = f2bf(v2);
    C[idx] = f2bf(v3);
    s1 += v1; q1 += v1 * v1;
    s2 += v2; q2 += v2 * v2;
    s3 += v3; q3 += v3 * v3;
  }
  int ri = (half * 128 + o) * 6;
  red[ri + 0] = s1; red[ri + 1] = q1; red[ri + 2] = s2;
  red[ri + 3] = q2; red[ri + 4] = s3; red[ri + 5] = q3;
  __syncthreads();
  if (half == 0) {
    int rj = (128 + o) * 6;
    atomicAdd(&sums[0 * 256 + o], s1 + red[rj + 0]);
    atomicAdd(&sums[0 * 256 + 128 + o], q1 + red[rj + 1]);
    atomicAdd(&sums[1 * 256 + o], s2 + red[rj + 2]);
    atomicAdd(&sums[1 * 256 + 128 + o], q2 + red[rj + 3]);
    atomicAdd(&sums[2 * 256 + o], s3 + red[rj + 4]);
    atomicAdd(&sums[2 * 256 + 128 + o], q3 + red[rj + 5]);
  }
}

// ---------------- CSR build (deg/rank already done in h2bf_deg) ----------------
__global__ void scan1(const int* __restrict__ deg, int* __restrict__ rp,
                      int* __restrict__ bs) {
  __shared__ int s[256];
  int t = threadIdx.x;
  int i = blockIdx.x * 256 + t;
  int v = deg[i];
  s[t] = v;
  for (int off = 1; off < 256; off <<= 1) {
    __syncthreads();
    int x = (t >= off) ? s[t - off] : 0;
    __syncthreads();
    s[t] += x;
  }
  rp[i] = s[t] - v;
  if (t == 255) bs[blockIdx.x] = s[255];
}

__global__ void scan2(int* __restrict__ bs) {
  __shared__ int s[512];
  int t = threadIdx.x;
  int v = bs[t];
  s[t] = v;
  for (int off = 1; off < 512; off <<= 1) {
    __syncthreads();
    int x = (t >= off) ? s[t - off] : 0;
    __syncthreads();
    s[t] += x;
  }
  bs[t] = s[t] - v;
}

__global__ void scan3(int* __restrict__ rp, const int* __restrict__ bs) {
  int i = blockIdx.x * 256 + threadIdx.x;
  rp[i] = rp[i] + bs[blockIdx.x];
  if (i == 0) rp[NN] = NE;
}

// packed entry: src in bits 0..16, weight q15 in bits 17..31 — NO atomics
__global__ void csr_fill2(const int* __restrict__ src, const int* __restrict__ dst,
                          const float* __restrict__ ew, const int* __restrict__ rp,
                          const u16* __restrict__ re, u32* __restrict__ csrP) {
  int e = blockIdx.x * 256 + threadIdx.x;
  if (e < NE) {
    int d = dst[e];
    int p = rp[d] + (int)re[e];
    u32 q = (u32)(ew[e] * 32767.f + 0.5f);
    csrP[p] = (u32)src[e] | (q << 17);
  }
}

// ---- fused stage-1: gather (F12 pair-interleaved + F3) + press + BN stats -> P ----
// AB3=8: 24 gather loads in flight per wave (2x R6 MLP). z1/z2 lines adjacent.
#define AB3 8
__global__ __launch_bounds__(256, 4) void agg3_press(
    const unsigned char* __restrict__ z12, const unsigned char* __restrict__ z3,
    const u32* __restrict__ csrP, const int* __restrict__ rp,
    const float* __restrict__ cp, const float* __restrict__ b1,
    const float* __restrict__ b2, const float* __restrict__ b3,
    const float* __restrict__ pw, const float* __restrict__ pb,
    u16* __restrict__ P, float* __restrict__ sums) {
  __shared__ u16 otile[4][16 * 128];    // 16 KB: per-wave output rows (bf16)
  __shared__ int ls_rp[4][17];
  int lane = threadIdx.x & 63, wave = threadIdx.x >> 6;
  int d0 = blockIdx.x * 64 + wave * 16;
  if (lane < 17) ls_rp[wave][lane] = rp[d0 + lane];
  float c1x = cp[lane * 2], c1y = cp[lane * 2 + 1];
  float c2x = cp[128 + lane * 2], c2y = cp[128 + lane * 2 + 1];
  float c3x = cp[256 + lane * 2], c3y = cp[256 + lane * 2 + 1];
  float b1x = b1[lane * 2], b1y = b1[lane * 2 + 1];
  float b2x = b2[lane * 2], b2y = b2[lane * 2 + 1];
  float b3x = b3[lane * 2], b3y = b3[lane * 2 + 1];
  float w10 = pw[0], w11 = pw[1], w12 = pw[2];
  float w20 = pw[3], w21 = pw[4], w22 = pw[5];
  float w30 = pw[6], w31 = pw[7], w32 = pw[8];
  float pbv = pb[0];
  __syncthreads();
  int s0 = __builtin_amdgcn_readfirstlane(ls_rp[wave][0]);
  int e0 = __builtin_amdgcn_readfirstlane(ls_rp[wave][16]);
  u32 vob = (u32)(lane * 2);
  float ax1 = 0.f, ay1 = 0.f, ax2 = 0.f, ay2 = 0.f, ax3 = 0.f, ay3 = 0.f;
  float wsum = 0.f;
  float sx = 0.f, qx = 0.f, sy = 0.f, qy = 0.f;
  int ld = 0;
  int nb = __builtin_amdgcn_readfirstlane(ls_rp[wave][1]);

  auto flush = [&]() {
    float swd = wsum;
    float a1x = fmaxf(ax1 + c1x * swd + b1x, 0.f);
    float a1y = fmaxf(ay1 + c1y * swd + b1y, 0.f);
    float a2x = fmaxf(ax2 + c2x * swd + b2x, 0.f);
    float a2y = fmaxf(ay2 + c2y * swd + b2y, 0.f);
    float a3x = fmaxf(ax3 + c3x * swd + b3x, 0.f);
    float a3y = fmaxf(ay3 + c3y * swd + b3y, 0.f);
    float l1 = __shfl_up(a1y, 1); if (lane == 0) l1 = 0.f;
    float l2 = __shfl_up(a2y, 1); if (lane == 0) l2 = 0.f;
    float l3 = __shfl_up(a3y, 1); if (lane == 0) l3 = 0.f;
    float r1 = __shfl_down(a1x, 1); if (lane == 63) r1 = 0.f;
    float r2 = __shfl_down(a2x, 1); if (lane == 63) r2 = 0.f;
    float r3 = __shfl_down(a3x, 1); if (lane == 63) r3 = 0.f;
    float ox = w10 * l1 + w11 * a1x + w12 * a1y + w20 * l2 + w21 * a2x +
               w22 * a2y + w30 * l3 + w31 * a3x + w32 * a3y + pbv;
    float oy = w10 * a1x + w11 * a1y + w12 * r1 + w20 * a2x + w21 * a2y +
               w22 * r2 + w30 * a3x + w31 * a3y + w32 * r3 + pbv;
    u32 pk2 = ((u32)f2bf(oy) << 16) | (u32)f2bf(ox);
    *(u32*)&otile[wave][ld * 128 + lane * 2] = pk2;   // LDS only — no vmem
    sx += ox; qx += ox * ox;
    sy += oy; qy += oy * oy;
    ax1 = ay1 = ax2 = ay2 = ax3 = ay3 = 0.f;
    wsum = 0.f;
    ++ld;
    nb = __builtin_amdgcn_readfirstlane(ls_rp[wave][ld < 16 ? ld + 1 : 16]);
  };

  if (s0 < e0) {
    int e0m1 = e0 - 1;
    u32 pkA[AB3], pkB[AB3];
    u32 vaA[AB3], vbA[AB3], vcA[AB3], vaB[AB3], vbB[AB3], vcB[AB3];
    float wvA[AB3], wvB[AB3];

// uniform (scalar) CSR reads — constant-cache s_loads
#define LOADPK3(PK, J0)                               \
  _Pragma("unroll") for (int k = 0; k < AB3; ++k) {   \
    int jc = (J0) + k;                                \
    jc = jc < e0 ? jc : e0m1;                         \
    PK[k] = csrP[jc];                                 \
  }
#define ISSUE3(VA, VB, VC, WV, PK)                    \
  _Pragma("unroll") for (int k = 0; k < AB3; ++k) {   \
    u32 p = PK[k];                                    \
    u32 sidx = p & 0x1FFFFu;                          \
    u32 off12 = (sidx << 8) | vob;                    \
    u32 off3 = (sidx << 7) | vob;                     \
    VA[k] = *(const u16*)(z12 + off12);               \
    VB[k] = *(const u16*)(z12 + off12 + 128);         \
    VC[k] = *(const u16*)(z3 + off3);                 \
    WV[k] = (float)(p >> 17) * WDQ;                   \
  }
#define CONS3(VA, VB, VC, WV, J0)                     \
  _Pragma("unroll") for (int k = 0; k < AB3; ++k) {   \
    int j = (J0) + k;                                 \
    if (j < e0) {                                     \
      while (j >= nb) flush();                        \
      float w = WV[k];                                \
      wsum += w;                                      \
      f32x2 d1 = __builtin_amdgcn_cvt_pk_f32_fp8((int)VA[k], false); \
      f32x2 d2 = __builtin_amdgcn_cvt_pk_f32_fp8((int)VB[k], false); \
      f32x2 d3 = __builtin_amdgcn_cvt_pk_f32_fp8((int)VC[k], false); \
      ax1 += d1.x * w; ay1 += d1.y * w;               \
      ax2 += d2.x * w; ay2 += d2.y * w;               \
      ax3 += d3.x * w; ay3 += d3.y * w;               \
    }                                                 \
  }

    LOADPK3(pkA, s0)
    ISSUE3(vaA, vbA, vcA, wvA, pkA)
    LOADPK3(pkA, s0 + AB3)
    int jb = s0;
    while (true) {
      LOADPK3(pkB, jb + 2 * AB3)
      if (jb + AB3 < e0) { ISSUE3(vaB, vbB, vcB, wvB, pkA) }
      CONS3(vaA, vbA, vcA, wvA, jb)
      if (jb + AB3 >= e0) break;
      LOADPK3(pkA, jb + 3 * AB3)
      if (jb + 2 * AB3 < e0) { ISSUE3(vaA, vbA, vcA, wvA, pkB) }
      CONS3(vaB, vbB, vcB, wvB, jb + AB3)
      if (jb + 2 * AB3 >= e0) break;
      jb += 2 * AB3;
    }
#undef LOADPK3
#undef ISSUE3
#undef CONS3
  }
  while (ld < 16) flush();

  // epilogue: coalesced copy of the wave's 4 KB tile -> P
  {
    const u16* srcl = &otile[wave][0];
    u16* dstg = P + (size_t)d0 * 128;
#pragma unroll
    for (int i = 0; i < 4; ++i) {
      uint4 v = *(const uint4*)(srcl + i * 512 + lane * 8);
      *(uint4*)(dstg + i * 512 + lane * 8) = v;
    }
  }
  __syncthreads();
  float* red = (float*)&otile[0][0];  // tile data already drained
  int base = wave * 256 + lane * 4;
  red[base] = sx; red[base + 1] = qx; red[base + 2] = sy; red[base + 3] = qy;
  __syncthreads();
  int t = threadIdx.x;
  if (t < 64) {
    float s0_ = 0, q0_ = 0, s1_ = 0, q1_ = 0;
#pragma unroll
    for (int w = 0; w < 4; ++w) {
      int rb = w * 256 + t * 4;
      s0_ += red[rb]; q0_ += red[rb + 1]; s1_ += red[rb + 2]; q1_ += red[rb + 3];
    }
    atomicAdd(&sums[768 + t * 2], s0_);
    atomicAdd(&sums[768 + 128 + t * 2], q0_);
    atomicAdd(&sums[768 + t * 2 + 1], s1_);
    atomicAdd(&sums[768 + 128 + t * 2 + 1], q1_);
  }
}

// ---- stage-2 aggregation (fp8 gather, AB2=16 MLP) + epilogue pooling ----
#define AB2 16
__global__ __launch_bounds__(256, 4) void agg2(const unsigned char* __restrict__ z,
                                               const u32* __restrict__ csrP,
                                               const int* __restrict__ rp,
                                               const float* __restrict__ cvec,
                                               const float* __restrict__ bvec,
                                               u16* __restrict__ out,
                                               const int* __restrict__ gid,
                                               float* __restrict__ hg, int coloff) {
  __shared__ u16 otile[4][16 * 128];
  __shared__ int ls_rp[4][17];
  __shared__ int ls_gid[4][16];
  int lane = threadIdx.x & 63, wave = threadIdx.x >> 6;
  int d0 = blockIdx.x * 64 + wave * 16;
  if (lane < 17) ls_rp[wave][lane] = rp[d0 + lane];
  if (lane < 16) ls_gid[wave][lane] = gid[d0 + lane];
  float bx = bvec[lane * 2], by = bvec[lane * 2 + 1];
  float cx = cvec ? cvec[lane * 2] : 0.f;
  float cy = cvec ? cvec[lane * 2 + 1] : 0.f;
  __syncthreads();
  int s0 = __builtin_amdgcn_readfirstlane(ls_rp[wave][0]);
  int e0 = __builtin_amdgcn_readfirstlane(ls_rp[wave][16]);
  u32 vob = (u32)(lane * 2);
  float ax = 0.f, ay = 0.f, wsum = 0.f;
  int ld = 0;
  int nb = __builtin_amdgcn_readfirstlane(ls_rp[wave][1]);

  auto flush = [&]() {
    float rx = fmaxf(ax + cx * wsum + bx, 0.f);
    float ry = fmaxf(ay + cy * wsum + by, 0.f);
    u32 pk2 = ((u32)f2bf(ry) << 16) | (u32)f2bf(rx);
    *(u32*)&otile[wave][ld * 128 + lane * 2] = pk2;   // LDS only — no vmem
    ax = 0.f;
    ay = 0.f;
    wsum = 0.f;
    ++ld;
    nb = __builtin_amdgcn_readfirstlane(ls_rp[wave][ld < 16 ? ld + 1 : 16]);
  };

  if (s0 < e0) {
    int e0m1 = e0 - 1;
    u32 pkA[AB2], pkB[AB2];
    u32 vaA[AB2], vaB[AB2];
    float wvA[AB2], wvB[AB2];

#define LOADPK1(PK, J0)                               \
  _Pragma("unroll") for (int k = 0; k < AB2; ++k) {   \
    int jc = (J0) + k;                                \
    jc = jc < e0 ? jc : e0m1;                         \
    PK[k] = csrP[jc];                                 \
  }
#define ISSUE1(VA, WV, PK)                            \
  _Pragma("unroll") for (int k = 0; k < AB2; ++k) {   \
    u32 p = PK[k];                                    \
    u32 off = ((p & 0x1FFFFu) << 7) | vob;            \
    VA[k] = *(const u16*)(z + off);                   \
    WV[k] = (float)(p >> 17) * WDQ;                   \
  }
#define CONS1(VA, WV, J0)                             \
  _Pragma("unroll") for (int k = 0; k < AB2; ++k) {   \
    int j = (J0) + k;                                 \
    if (j < e0) {                                     \
      while (j >= nb) flush();                        \
      float w = WV[k];                                \
      wsum += w;                                      \
      f32x2 d = __builtin_amdgcn_cvt_pk_f32_fp8((int)VA[k], false); \
      ax += d.x * w;                                  \
      ay += d.y * w;                                  \
    }                                                 \
  }

    LOADPK1(pkA, s0)
    ISSUE1(vaA, wvA, pkA)
    LOADPK1(pkA, s0 + AB2)
    int jb = s0;
    while (true) {
      LOADPK1(pkB, jb + 2 * AB2)
      if (jb + AB2 < e0) { ISSUE1(vaB, wvB, pkA) }
      CONS1(vaA, wvA, jb)
      if (jb + AB2 >= e0) break;
      LOADPK1(pkA, jb + 3 * AB2)
      if (jb + 2 * AB2 < e0) { ISSUE1(vaA, wvA, pkB) }
      CONS1(vaB, wvB, jb + AB2)
      if (jb + 2 * AB2 >= e0) break;
      jb += 2 * AB2;
    }
#undef LOADPK1
#undef ISSUE1
#undef CONS1
  }
  while (ld < 16) flush();

  // epilogue 1: coalesced copy of the wave's tile -> out
  {
    const u16* srcl = &otile[wave][0];
    u16* dstg = out + (size_t)d0 * 128;
#pragma unroll
    for (int i = 0; i < 4; ++i) {
      uint4 v = *(const uint4*)(srcl + i * 512 + lane * 8);
      *(uint4*)(dstg + i * 512 + lane * 8) = v;
    }
  }
  // epilogue 2: per-graph pooling from the tile (atomics out of the hot loop)
  {
    float runx = 0.f, runy = 0.f;
    int curg = __builtin_amdgcn_readfirstlane(ls_gid[wave][0]);
    for (int r = 0; r < 16; ++r) {
      u32 v = *(const u32*)&otile[wave][r * 128 + lane * 2];
      float rx = blo(v), ry = bhi(v);
      int gn = __builtin_amdgcn_readfirstlane(ls_gid[wave][r]);
      if (gn != curg) {
        atomicAdd(&hg[curg * 384 + coloff + lane * 2], runx);
        atomicAdd(&hg[curg * 384 + coloff + lane * 2 + 1], runy);
        runx = 0.f;
        runy = 0.f;
        curg = gn;
      }
      runx += rx;
      runy += ry;
    }
    atomicAdd(&hg[curg * 384 + coloff + lane * 2], runx);
    atomicAdd(&hg[curg * 384 + coloff + lane * 2 + 1], runy);
  }
}

// ---------------- classifier ----------------
__global__ void classifier(const float* __restrict__ hg, const float* __restrict__ w1,
                           const float* __restrict__ b1, const float* __restrict__ w2,
                           const float* __restrict__ b2, float* __restrict__ out) {
  __shared__ float sh_hg[16 * 384];
  __shared__ float sh_z[16 * 128];
  int t = threadIdx.x;
  for (int u = t; u < 16 * 384; u += 256) sh_hg[u] = hg[u];
  __syncthreads();
  for (int u = 0; u < 8; ++u) {
    int idx = t + u * 256;
    int b = idx >> 7, o = idx & 127;
    float a = b1[o];
    for (int i = 0; i < 384; ++i) a += sh_hg[b * 384 + i] * w1[o * 384 + i];
    sh_z[b * 128 + o] = a;
  }
  __syncthreads();
  if (t < 80) {
    int b = t / 5, c = t % 5;
    float a = b2[c];
    for (int i = 0; i < 128; ++i) a += sh_z[b * 128 + i] * w2[c * 128 + i];
    out[b * 5 + c] = a;
  }
}

extern "C" void kernel_launch(void* const* d_in, const int* in_sizes, int n_in,
                              void* d_out, int out_size, void* d_ws, size_t ws_size,
                              hipStream_t stream) {
  const float* h = (const float*)d_in[0];
  const float* edge_w = (const float*)d_in[1];
  const int* src = (const int*)d_in[2];
  const int* dst = (const int*)d_in[3];
  const int* gid = (const int*)d_in[4];
  const float* c1w = (const float*)d_in[6];
  const float* c1b = (const float*)d_in[7];
  const float* c2w = (const float*)d_in[8];
  const float* c2b = (const float*)d_in[9];
  const float* c3w = (const float*)d_in[10];
  const float* c3b = (const float*)d_in[11];
  const float* pw = (const float*)d_in[12];
  const float* pb = (const float*)d_in[13];
  const float* g11w = (const float*)d_in[14];
  const float* g11b = (const float*)d_in[15];
  const float* g12w = (const float*)d_in[16];
  const float* g12b = (const float*)d_in[17];
  const float* g13w = (const float*)d_in[18];
  const float* g13b = (const float*)d_in[19];
  const float* g2w = (const float*)d_in[20];
  const float* g2b = (const float*)d_in[21];
  const float* g3w = (const float*)d_in[22];
  const float* g3b = (const float*)d_in[23];
  const float* g4w = (const float*)d_in[24];
  const float* g4b = (const float*)d_in[25];
  const float* bng = (const float*)d_in[26];
  const float* bnb = (const float*)d_in[27];
  const float* cl1w = (const float*)d_in[28];
  const float* cl1b = (const float*)d_in[29];
  const float* cl2w = (const float*)d_in[30];
  const float* cl2b = (const float*)d_in[31];

  char* ws = (char*)d_ws;
  u16* H16 = (u16*)(ws + H16_OFF);
  u16* A = (u16*)(ws + A_OFF);
  u16* B = (u16*)(ws + B_OFF);
  u16* C = (u16*)(ws + C_OFF);
  unsigned char* F12 = (unsigned char*)(ws + H16_OFF);  // fp8 [N][256], 32 MB
  unsigned char* F3 = (unsigned char*)(ws + Z_OFF);     // fp8 [N][128], 16 MB
  unsigned char* FS2 = (unsigned char*)(ws + H16_OFF);  // stage-2 fp8 [N][128]
  u16* re = (u16*)(ws + RE_OFF);  // edge ranks (dead before F3 written)
  u16* P = (u16*)(ws + A_OFF);    // bf16 press output (A's t1 dead by then)
  u32* csrP = (u32*)(ws + CSR_OFF);
  int* rp = (int*)(ws + RP_OFF);
  int* deg = (int*)(ws + DEG_OFF);
  int* bs = (int*)(ws + BS_OFF);
  float* sums = (float*)(ws + SUMS_OFF);
  float* hg = (float*)(ws + HG_OFF);
  u16* wT16 = (u16*)(ws + WT16_OFF);
  u16* wP16 = (u16*)(ws + WP16_OFF);
  float* cp = (float*)(ws + CP_OFF);
  float* sv = (float*)(ws + SV_OFF);
  float* shv = (float*)(ws + SHV_OFF);
  float* outp = (float*)d_out;

  zerok<<<512, 256, 0, stream>>>(deg, sums, hg);
  h2bf_deg<<<8192, 256, 0, stream>>>(h, H16, dst, deg, re);
  prep_wT16<<<1728, 256, 0, stream>>>(c1w, c2w, c3w, wT16);
  wprep16<<<64, 256, 0, stream>>>(g3w, (const float*)nullptr, wP16 + 4 * 17408);
  wprep16<<<64, 256, 0, stream>>>(g4w, (const float*)nullptr, wP16 + 5 * 17408);

  mfma_gemm<3, 1, 0><<<1024, 256, 0, stream>>>(H16, wT16 + 0 * 52224, A, 0);
  mfma_gemm<3, 2, 0><<<1024, 256, 0, stream>>>(H16, wT16 + 1 * 52224, B, 0);
  mfma_gemm<3, 3, 0><<<1024, 256, 0, stream>>>(H16, wT16 + 2 * 52224, C, 0);
  combine<<<4096, 256, 0, stream>>>(A, B, C, c1b, c2b, c3b, sums);

  // CSR placement (deg+rank already computed in h2bf_deg)
  scan1<<<512, 256, 0, stream>>>(deg, rp, bs);
  scan2<<<1, 512, 0, stream>>>(bs);
  scan3<<<512, 256, 0, stream>>>(rp, bs);
  csr_fill2<<<8192, 256, 0, stream>>>(src, dst, edge_w, rp, re, csrP);

  bnparam<<<3, 128, 0, stream>>>(sums, bng, bnb, sv, shv, 0);
  wprep16<<<64, 256, 0, stream>>>(g11w, sv + 0 * 128, wP16 + 0 * 17408);
  cprep<<<1, 128, 0, stream>>>(g11w, shv + 0 * 128, cp + 0 * 128);
  wprep16<<<64, 256, 0, stream>>>(g12w, sv + 1 * 128, wP16 + 1 * 17408);
  cprep<<<1, 128, 0, stream>>>(g12w, shv + 1 * 128, cp + 1 * 128);
  wprep16<<<64, 256, 0, stream>>>(g13w, sv + 2 * 128, wP16 + 2 * 17408);
  cprep<<<1, 128, 0, stream>>>(g13w, shv + 2 * 128, cp + 2 * 128);

  // stage 1: z1,z2 -> F12 pair-interleaved (stride 256, ch offsets 0/128);
  // z3 -> F3 (stride 128). Then fused agg+press -> P + BN stats(t3).
  mfma_gemm<1, 0, 1><<<1024, 256, 0, stream>>>(A, wP16 + 0 * 17408, (u16*)F12, 256);
  mfma_gemm<1, 0, 1><<<1024, 256, 0, stream>>>(B, wP16 + 1 * 17408, (u16*)(F12 + 128), 256);
  mfma_gemm<1, 0, 1><<<1024, 256, 0, stream>>>(C, wP16 + 2 * 17408, (u16*)F3, 128);
  agg3_press<<<2048, 256, 0, stream>>>(F12, F3, csrP, rp, cp, g11b, g12b,
                                       g13b, pw, pb, P, sums);

  bnparam<<<1, 128, 0, stream>>>(sums, bng, bnb, sv, shv, 3);
  wprep16<<<64, 256, 0, stream>>>(g2w, sv + 3 * 128, wP16 + 3 * 17408);
  cprep<<<1, 128, 0, stream>>>(g2w, shv + 3 * 128, cp + 3 * 128);

  // stage 2 chain: GEMM -> fp8 FS2 (H16 region, F12 dead), gather -> bf16 rows
  mfma_gemm<1, 0, 1><<<1024, 256, 0, stream>>>(P, wP16 + 3 * 17408, (u16*)FS2, 128);  // y2
  agg2<<<2048, 256, 0, stream>>>(FS2, csrP, rp, cp + 3 * 128, g2b, B, gid, hg, 0);
  mfma_gemm<1, 0, 1><<<1024, 256, 0, stream>>>(B, wP16 + 4 * 17408, (u16*)FS2, 128);  // y3
  agg2<<<2048, 256, 0, stream>>>(FS2, csrP, rp, (const float*)nullptr, g3b, C, gid, hg, 128);
  mfma_gemm<1, 0, 1><<<1024, 256, 0, stream>>>(C, wP16 + 5 * 17408, (u16*)FS2, 128);  // y4
  agg2<<<2048, 256, 0, stream>>>(FS2, csrP, rp, (const float*)nullptr, g4b, A, gid, hg, 256);

  classifier<<<1, 256, 0, stream>>>(hg, cl1w, cl1b, cl2w, cl2b, outp);
}

// Round 8
// 1201.468 us; speedup vs baseline: 1.0599x; 1.0599x over previous
//
#include <hip/hip_runtime.h>

#define NN 131072
#define NE 2097152

typedef unsigned short u16;
typedef unsigned int u32;
typedef __attribute__((ext_vector_type(8))) short bf16x8;
typedef __attribute__((ext_vector_type(4))) float f32x4;
typedef __attribute__((ext_vector_type(2))) float f32x2;

__device__ __forceinline__ float bf2f(u16 v) {
  unsigned u = ((unsigned)v) << 16;
  return __builtin_bit_cast(float, u);
}
__device__ __forceinline__ float blo(u32 v) {
  return __builtin_bit_cast(float, v << 16);
}
__device__ __forceinline__ float bhi(u32 v) {
  return __builtin_bit_cast(float, v & 0xffff0000u);
}
__device__ __forceinline__ u16 f2bf(float f) {
  unsigned u = __builtin_bit_cast(unsigned, f);
  unsigned r = (u + 0x7fffu + ((u >> 16) & 1u)) >> 16;
  return (u16)r;
}

#define WDQ 3.0518509475997192e-05f  // 1/32767

// ---------------- workspace layout (bytes) ----------------
// F12 (fp8 z1/z2 pair-interleaved [node][256]) = 32 MB = H16 region (dead
// after conv GEMMs). F3 (fp8 z3 [node][128]) = first 16 MB of Z region.
// re (u16 edge ranks) = second half of Z (dead before F3 written).
// FS2 (stage-2 fp8) overlays H16 (F12 dead after agg3_press). P = A region.
#define H16_OFF 0ull               // bf16 [N,128] 32 MB / later F12 fp8 [N,256]
#define A_OFF 33554432ull          // bf16 [N,128] 32 MB
#define B_OFF 67108864ull          // bf16
#define C_OFF 100663296ull         // bf16
#define Z_OFF 134217728ull         // 32 MB (first 16 MB = F3 fp8; re in 2nd half)
#define RE_OFF 150994944ull        // u16 [E] edge ranks
#define CSR_OFF 167772160ull       // E x u32 packed {src:17, w:15} = 8 MB
#define RP_OFF 184549376ull        // N+1 ints (reserve 528384)
#define DEG_OFF 185077760ull       // N ints
#define BS_OFF 186126336ull        // 512 ints (reserve 4096)
#define SUMS_OFF 186130432ull      // [4][2][128] f32
#define HG_OFF 186134528ull        // [16][384] f32
#define WT16_OFF 186159104ull      // conv w: 3 conv x 3 tap x 128 x 136 u16
#define WP16_OFF 186472448ull      // 6 mats x 128 x 136 u16
#define CP_OFF 186681344ull        // 4 x 128 f32
#define SV_OFF 186683392ull        // 4 x 128 f32
#define SHV_OFF 186685440ull       // 4 x 128 f32

// ---------------- zero-init (graph-capture safe) ----------------
__global__ void zerok(int* __restrict__ deg, float* __restrict__ sums,
                      float* __restrict__ hg) {
  int i = blockIdx.x * 256 + threadIdx.x;  // 512*256 = 131072
  deg[i] = 0;
  if (i < 1024) sums[i] = 0.f;
  if (i < 6144) hg[i] = 0.f;
}

// ---- h (f32) -> H16 (bf16), fused with per-edge deg count + rank ----
__global__ void h2bf_deg(const float* __restrict__ h, u16* __restrict__ o,
                         const int* __restrict__ dst, int* __restrict__ deg,
                         u16* __restrict__ re) {
  int i = blockIdx.x * 256 + threadIdx.x;  // x8 elements; also edge id
  float4 v0 = *(const float4*)(h + (size_t)i * 8);
  float4 v1 = *(const float4*)(h + (size_t)i * 8 + 4);
  ushort4 a, b;
  a.x = f2bf(v0.x); a.y = f2bf(v0.y); a.z = f2bf(v0.z); a.w = f2bf(v0.w);
  b.x = f2bf(v1.x); b.y = f2bf(v1.y); b.z = f2bf(v1.z); b.w = f2bf(v1.w);
  *(ushort4*)(o + (size_t)i * 8) = a;
  *(ushort4*)(o + (size_t)i * 8 + 4) = b;
  int d = dst[i];
  int r = atomicAdd(&deg[d], 1);
  re[i] = (u16)r;
}

// ---- conv weights -> bf16 transposed padded: [conv][tap][o=128][ipad=136] ----
__global__ void prep_wT16(const float* __restrict__ w1, const float* __restrict__ w2,
                          const float* __restrict__ w3, u16* __restrict__ wT) {
  int e = blockIdx.x * 256 + threadIdx.x;
  if (e >= 3 * 3 * 128 * 128) return;
  int o = e & 127;
  int i = (e >> 7) & 127;
  int ct = e >> 14;
  int t = ct % 3, c = ct / 3;
  const float* w = (c == 0) ? w1 : (c == 1) ? w2 : w3;
  wT[(size_t)(c * 3 + t) * 17408 + o * 136 + i] = f2bf(w[(o * 128 + i) * 3 + t]);
}

// ---- gemm weights -> bf16 transposed padded [o=128][ipad=136], opt. BN fold ----
__global__ void wprep16(const float* __restrict__ W, const float* __restrict__ sv,
                        u16* __restrict__ Wt) {
  int e = blockIdx.x * 256 + threadIdx.x;  // 16384
  int o = e & 127, i = e >> 7;
  float s = sv ? sv[i] : 1.f;
  Wt[o * 136 + i] = f2bf(s * W[i * 128 + o]);
}

__global__ void cprep(const float* __restrict__ W, const float* __restrict__ shv,
                      float* __restrict__ cp) {
  int j = threadIdx.x;
  float a = 0.f;
  for (int i = 0; i < 128; ++i) a += shv[i] * W[i * 128 + j];
  cp[j] = a;
}

// ---------------- BN params ----------------
__global__ void bnparam(const float* __restrict__ sums, const float* __restrict__ g,
                        const float* __restrict__ b, float* __restrict__ sv,
                        float* __restrict__ shv, int tensor0) {
  int t = tensor0 + blockIdx.x;
  int o = threadIdx.x;
  float mu = sums[t * 256 + o] / (float)NN;
  float var = sums[t * 256 + 128 + o] / (float)NN - mu * mu;
  float s = g[o] * rsqrtf(var + 1e-5f);
  sv[t * 128 + o] = s;
  shv[t * 128 + o] = b[o] - mu * s;
}

// ---------------- MFMA GEMM: z[n,:] = sum_t x[n+shift_t,:] @ W_t ----------------
// OUT8=1: output written as fp8 e4m3 bytes at node stride zsb (128 or 256)
template <int TAPS, int DIL, int OUT8>
__global__ __launch_bounds__(256, 4) void mfma_gemm(const u16* __restrict__ x,
                                                    const u16* __restrict__ wt,
                                                    u16* __restrict__ z, int zsb) {
  __shared__ u16 sh[17408];
  int tid = threadIdx.x;
  int lane = tid & 63, wave = tid >> 6;
  int n0 = blockIdx.x * 128;
  int m = lane & 15, quad = lane >> 4;
  int koff = quad * 8;
  f32x4 acc[2][8];
#pragma unroll
  for (int a = 0; a < 2; ++a)
#pragma unroll
    for (int b = 0; b < 8; ++b) acc[a][b] = (f32x4){0.f, 0.f, 0.f, 0.f};
  int rbase = n0 + wave * 32 + m;

  for (int t = 0; t < TAPS; ++t) {
    if (TAPS > 1) __syncthreads();
    for (int idx = tid; idx < 2176; idx += 256)
      ((uint4*)sh)[idx] = ((const uint4*)(wt + (size_t)t * 17408))[idx];
    __syncthreads();
    const int shift = (TAPS == 3) ? (t - 1) * DIL : 0;
#pragma unroll
    for (int ks = 0; ks < 4; ++ks) {
      bf16x8 af[2];
#pragma unroll
      for (int rt = 0; rt < 2; ++rt) {
        int row = rbase + rt * 16 + shift;
        if (TAPS == 3) {
          int rc = min(max(row, 0), NN - 1);
          bf16x8 v = *(const bf16x8*)(x + (size_t)rc * 128 + ks * 32 + koff);
          bf16x8 zz = {};
          af[rt] = (row >= 0 && row < NN) ? v : zz;
        } else {
          af[rt] = *(const bf16x8*)(x + (size_t)row * 128 + ks * 32 + koff);
        }
      }
#pragma unroll
      for (int ct = 0; ct < 8; ++ct) {
        bf16x8 bf = *(const bf16x8*)(sh + (ct * 16 + m) * 136 + ks * 32 + koff);
        acc[0][ct] =
            __builtin_amdgcn_mfma_f32_16x16x32_bf16(af[0], bf, acc[0][ct], 0, 0, 0);
        acc[1][ct] =
            __builtin_amdgcn_mfma_f32_16x16x32_bf16(af[1], bf, acc[1][ct], 0, 0, 0);
      }
    }
  }
  __syncthreads();
#pragma unroll
  for (int rt = 0; rt < 2; ++rt)
#pragma unroll
    for (int ct = 0; ct < 8; ++ct)
#pragma unroll
      for (int r = 0; r < 4; ++r) {
        int rowl = wave * 32 + rt * 16 + quad * 4 + r;
        sh[rowl * 136 + ct * 16 + m] = f2bf(acc[rt][ct][r]);
      }
  __syncthreads();
  if (OUT8) {
    unsigned char* z8 = (unsigned char*)z;
#pragma unroll
    for (int it = 0; it < 8; ++it) {
      int q = tid + it * 256;
      int row = q >> 4, g = q & 15;
      uint4 v = *(const uint4*)(sh + row * 136 + g * 8);
      int w0 = __builtin_amdgcn_cvt_pk_fp8_f32(blo(v.x), bhi(v.x), 0, false);
      w0 = __builtin_amdgcn_cvt_pk_fp8_f32(blo(v.y), bhi(v.y), w0, true);
      int w1 = __builtin_amdgcn_cvt_pk_fp8_f32(blo(v.z), bhi(v.z), 0, false);
      w1 = __builtin_amdgcn_cvt_pk_fp8_f32(blo(v.w), bhi(v.w), w1, true);
      uint2 st;
      st.x = (u32)w0;
      st.y = (u32)w1;
      *(uint2*)(z8 + (size_t)(n0 + row) * zsb + g * 8) = st;
    }
  } else {
#pragma unroll
    for (int it = 0; it < 8; ++it) {
      int q = tid + it * 256;
      int row = q >> 4, g = q & 15;
      uint4 v = *(const uint4*)(sh + row * 136 + g * 8);
      *(uint4*)(z + (size_t)(n0 + row) * 128 + g * 8) = v;
    }
  }
}

// ------- combine: t1=relu(c1)+c2, t2=relu(c2)+c3, t3=relu(c3)+c1 (bf16 in-place) ---
__global__ __launch_bounds__(256) void combine(u16* __restrict__ A, u16* __restrict__ B,
                                               u16* __restrict__ C,
                                               const float* __restrict__ b1,
                                               const float* __restrict__ b2,
                                               const float* __restrict__ b3,
                                               float* __restrict__ sums) {
  __shared__ float red[2 * 128 * 6];
  int tid = threadIdx.x;
  int o = tid & 127, half = tid >> 7;
  int n0 = blockIdx.x * 32 + half * 16;
  float bb1 = b1[o], bb2 = b2[o], bb3 = b3[o];
  float s1 = 0, q1 = 0, s2 = 0, q2 = 0, s3 = 0, q3 = 0;
  for (int j = 0; j < 16; ++j) {
    size_t idx = (size_t)(n0 + j) * 128 + o;
    float c1 = bf2f(A[idx]) + bb1, c2 = bf2f(B[idx]) + bb2, c3 = bf2f(C[idx]) + bb3;
    float v1 = fmaxf(c1, 0.f) + c2;
    float v2 = fmaxf(c2, 0.f) + c3;
    float v3 = fmaxf(c3, 0.f) + c1;
    A[idx] = f2bf(v1);
    B[idx] = f2bf(v2);
    C[idx] = f2bf(v3);
    s1 += v1; q1 += v1 * v1;
    s2 += v2; q2 += v2 * v2;
    s3 += v3; q3 += v3 * v3;
  }
  int ri = (half * 128 + o) * 6;
  red[ri + 0] = s1; red[ri + 1] = q1; red[ri + 2] = s2;
  red[ri + 3] = q2; red[ri + 4] = s3; red[ri + 5] = q3;
  __syncthreads();
  if (half == 0) {
    int rj = (128 + o) * 6;
    atomicAdd(&sums[0 * 256 + o], s1 + red[rj + 0]);
    atomicAdd(&sums[0 * 256 + 128 + o], q1 + red[rj + 1]);
    atomicAdd(&sums[1 * 256 + o], s2 + red[rj + 2]);
    atomicAdd(&sums[1 * 256 + 128 + o], q2 + red[rj + 3]);
    atomicAdd(&sums[2 * 256 + o], s3 + red[rj + 4]);
    atomicAdd(&sums[2 * 256 + 128 + o], q3 + red[rj + 5]);
  }
}

// ---------------- CSR build (deg/rank already done in h2bf_deg) ----------------
__global__ void scan1(const int* __restrict__ deg, int* __restrict__ rp,
                      int* __restrict__ bs) {
  __shared__ int s[256];
  int t = threadIdx.x;
  int i = blockIdx.x * 256 + t;
  int v = deg[i];
  s[t] = v;
  for (int off = 1; off < 256; off <<= 1) {
    __syncthreads();
    int x = (t >= off) ? s[t - off] : 0;
    __syncthreads();
    s[t] += x;
  }
  rp[i] = s[t] - v;
  if (t == 255) bs[blockIdx.x] = s[255];
}

__global__ void scan2(int* __restrict__ bs) {
  __shared__ int s[512];
  int t = threadIdx.x;
  int v = bs[t];
  s[t] = v;
  for (int off = 1; off < 512; off <<= 1) {
    __syncthreads();
    int x = (t >= off) ? s[t - off] : 0;
    __syncthreads();
    s[t] += x;
  }
  bs[t] = s[t] - v;
}

__global__ void scan3(int* __restrict__ rp, const int* __restrict__ bs) {
  int i = blockIdx.x * 256 + threadIdx.x;
  rp[i] = rp[i] + bs[blockIdx.x];
  if (i == 0) rp[NN] = NE;
}

// packed entry: src in bits 0..16, weight q15 in bits 17..31 — NO atomics
__global__ void csr_fill2(const int* __restrict__ src, const int* __restrict__ dst,
                          const float* __restrict__ ew, const int* __restrict__ rp,
                          const u16* __restrict__ re, u32* __restrict__ csrP) {
  int e = blockIdx.x * 256 + threadIdx.x;
  if (e < NE) {
    int d = dst[e];
    int p = rp[d] + (int)re[e];
    u32 q = (u32)(ew[e] * 32767.f + 0.5f);
    csrP[p] = (u32)src[e] | (q << 17);
  }
}

// ---- fused stage-1: gather (F12 pair-interleaved + F3) + press + BN stats -> P ----
// AB3=4 (R6 register footprint, no spill); z1/z2 lines adjacent via F12.
#define AB3 4
__global__ __launch_bounds__(256, 4) void agg3_press(
    const unsigned char* __restrict__ z12, const unsigned char* __restrict__ z3,
    const u32* __restrict__ csrP, const int* __restrict__ rp,
    const float* __restrict__ cp, const float* __restrict__ b1,
    const float* __restrict__ b2, const float* __restrict__ b3,
    const float* __restrict__ pw, const float* __restrict__ pb,
    u16* __restrict__ P, float* __restrict__ sums) {
  __shared__ u16 otile[4][16 * 128];    // 16 KB: per-wave output rows (bf16)
  __shared__ int ls_rp[4][17];
  int lane = threadIdx.x & 63, wave = threadIdx.x >> 6;
  int d0 = blockIdx.x * 64 + wave * 16;
  if (lane < 17) ls_rp[wave][lane] = rp[d0 + lane];
  float c1x = cp[lane * 2], c1y = cp[lane * 2 + 1];
  float c2x = cp[128 + lane * 2], c2y = cp[128 + lane * 2 + 1];
  float c3x = cp[256 + lane * 2], c3y = cp[256 + lane * 2 + 1];
  float b1x = b1[lane * 2], b1y = b1[lane * 2 + 1];
  float b2x = b2[lane * 2], b2y = b2[lane * 2 + 1];
  float b3x = b3[lane * 2], b3y = b3[lane * 2 + 1];
  float w10 = pw[0], w11 = pw[1], w12 = pw[2];
  float w20 = pw[3], w21 = pw[4], w22 = pw[5];
  float w30 = pw[6], w31 = pw[7], w32 = pw[8];
  float pbv = pb[0];
  __syncthreads();
  int s0 = __builtin_amdgcn_readfirstlane(ls_rp[wave][0]);
  int e0 = __builtin_amdgcn_readfirstlane(ls_rp[wave][16]);
  u32 vob = (u32)(lane * 2);
  float ax1 = 0.f, ay1 = 0.f, ax2 = 0.f, ay2 = 0.f, ax3 = 0.f, ay3 = 0.f;
  float wsum = 0.f;
  float sx = 0.f, qx = 0.f, sy = 0.f, qy = 0.f;
  int ld = 0;
  int nb = __builtin_amdgcn_readfirstlane(ls_rp[wave][1]);

  auto flush = [&]() {
    float swd = wsum;
    float a1x = fmaxf(ax1 + c1x * swd + b1x, 0.f);
    float a1y = fmaxf(ay1 + c1y * swd + b1y, 0.f);
    float a2x = fmaxf(ax2 + c2x * swd + b2x, 0.f);
    float a2y = fmaxf(ay2 + c2y * swd + b2y, 0.f);
    float a3x = fmaxf(ax3 + c3x * swd + b3x, 0.f);
    float a3y = fmaxf(ay3 + c3y * swd + b3y, 0.f);
    float l1 = __shfl_up(a1y, 1); if (lane == 0) l1 = 0.f;
    float l2 = __shfl_up(a2y, 1); if (lane == 0) l2 = 0.f;
    float l3 = __shfl_up(a3y, 1); if (lane == 0) l3 = 0.f;
    float r1 = __shfl_down(a1x, 1); if (lane == 63) r1 = 0.f;
    float r2 = __shfl_down(a2x, 1); if (lane == 63) r2 = 0.f;
    float r3 = __shfl_down(a3x, 1); if (lane == 63) r3 = 0.f;
    float ox = w10 * l1 + w11 * a1x + w12 * a1y + w20 * l2 + w21 * a2x +
               w22 * a2y + w30 * l3 + w31 * a3x + w32 * a3y + pbv;
    float oy = w10 * a1x + w11 * a1y + w12 * r1 + w20 * a2x + w21 * a2y +
               w22 * r2 + w30 * a3x + w31 * a3y + w32 * r3 + pbv;
    u32 pk2 = ((u32)f2bf(oy) << 16) | (u32)f2bf(ox);
    *(u32*)&otile[wave][ld * 128 + lane * 2] = pk2;   // LDS only — no vmem
    sx += ox; qx += ox * ox;
    sy += oy; qy += oy * oy;
    ax1 = ay1 = ax2 = ay2 = ax3 = ay3 = 0.f;
    wsum = 0.f;
    ++ld;
    nb = __builtin_amdgcn_readfirstlane(ls_rp[wave][ld < 16 ? ld + 1 : 16]);
  };

  if (s0 < e0) {
    int e0m1 = e0 - 1;
    u32 pkA[AB3], pkB[AB3];
    u32 vaA[AB3], vbA[AB3], vcA[AB3], vaB[AB3], vbB[AB3], vcB[AB3];
    float wvA[AB3], wvB[AB3];

// uniform (scalar) CSR reads — constant-cache s_loads
#define LOADPK3(PK, J0)                               \
  _Pragma("unroll") for (int k = 0; k < AB3; ++k) {   \
    int jc = (J0) + k;                                \
    jc = jc < e0 ? jc : e0m1;                         \
    PK[k] = csrP[jc];                                 \
  }
#define ISSUE3(VA, VB, VC, WV, PK)                    \
  _Pragma("unroll") for (int k = 0; k < AB3; ++k) {   \
    u32 p = PK[k];                                    \
    u32 sidx = p & 0x1FFFFu;                          \
    u32 off12 = (sidx << 8) | vob;                    \
    u32 off3 = (sidx << 7) | vob;                     \
    VA[k] = *(const u16*)(z12 + off12);               \
    VB[k] = *(const u16*)(z12 + off12 + 128);         \
    VC[k] = *(const u16*)(z3 + off3);                 \
    WV[k] = (float)(p >> 17) * WDQ;                   \
  }
#define CONS3(VA, VB, VC, WV, J0)                     \
  _Pragma("unroll") for (int k = 0; k < AB3; ++k) {   \
    int j = (J0) + k;                                 \
    if (j < e0) {                                     \
      while (j >= nb) flush();                        \
      float w = WV[k];                                \
      wsum += w;                                      \
      f32x2 d1 = __builtin_amdgcn_cvt_pk_f32_fp8((int)VA[k], false); \
      f32x2 d2 = __builtin_amdgcn_cvt_pk_f32_fp8((int)VB[k], false); \
      f32x2 d3 = __builtin_amdgcn_cvt_pk_f32_fp8((int)VC[k], false); \
      ax1 += d1.x * w; ay1 += d1.y * w;               \
      ax2 += d2.x * w; ay2 += d2.y * w;               \
      ax3 += d3.x * w; ay3 += d3.y * w;               \
    }                                                 \
  }

    LOADPK3(pkA, s0)
    ISSUE3(vaA, vbA, vcA, wvA, pkA)
    LOADPK3(pkA, s0 + AB3)
    int jb = s0;
    while (true) {
      LOADPK3(pkB, jb + 2 * AB3)
      if (jb + AB3 < e0) { ISSUE3(vaB, vbB, vcB, wvB, pkA) }
      CONS3(vaA, vbA, vcA, wvA, jb)
      if (jb + AB3 >= e0) break;
      LOADPK3(pkA, jb + 3 * AB3)
      if (jb + 2 * AB3 < e0) { ISSUE3(vaA, vbA, vcA, wvA, pkB) }
      CONS3(vaB, vbB, vcB, wvB, jb + AB3)
      if (jb + 2 * AB3 >= e0) break;
      jb += 2 * AB3;
    }
#undef LOADPK3
#undef ISSUE3
#undef CONS3
  }
  while (ld < 16) flush();

  // epilogue: coalesced copy of the wave's 4 KB tile -> P
  {
    const u16* srcl = &otile[wave][0];
    u16* dstg = P + (size_t)d0 * 128;
#pragma unroll
    for (int i = 0; i < 4; ++i) {
      uint4 v = *(const uint4*)(srcl + i * 512 + lane * 8);
      *(uint4*)(dstg + i * 512 + lane * 8) = v;
    }
  }
  __syncthreads();
  float* red = (float*)&otile[0][0];  // tile data already drained
  int base = wave * 256 + lane * 4;
  red[base] = sx; red[base + 1] = qx; red[base + 2] = sy; red[base + 3] = qy;
  __syncthreads();
  int t = threadIdx.x;
  if (t < 64) {
    float s0_ = 0, q0_ = 0, s1_ = 0, q1_ = 0;
#pragma unroll
    for (int w = 0; w < 4; ++w) {
      int rb = w * 256 + t * 4;
      s0_ += red[rb]; q0_ += red[rb + 1]; s1_ += red[rb + 2]; q1_ += red[rb + 3];
    }
    atomicAdd(&sums[768 + t * 2], s0_);
    atomicAdd(&sums[768 + 128 + t * 2], q0_);
    atomicAdd(&sums[768 + t * 2 + 1], s1_);
    atomicAdd(&sums[768 + 128 + t * 2 + 1], q1_);
  }
}

// ---- stage-2 aggregation (fp8 gather, AB2=8) + epilogue pooling ----
#define AB2 8
__global__ __launch_bounds__(256, 4) void agg2(const unsigned char* __restrict__ z,
                                               const u32* __restrict__ csrP,
                                               const int* __restrict__ rp,
                                               const float* __restrict__ cvec,
                                               const float* __restrict__ bvec,
                                               u16* __restrict__ out,
                                               const int* __restrict__ gid,
                                               float* __restrict__ hg, int coloff) {
  __shared__ u16 otile[4][16 * 128];
  __shared__ int ls_rp[4][17];
  __shared__ int ls_gid[4][16];
  int lane = threadIdx.x & 63, wave = threadIdx.x >> 6;
  int d0 = blockIdx.x * 64 + wave * 16;
  if (lane < 17) ls_rp[wave][lane] = rp[d0 + lane];
  if (lane < 16) ls_gid[wave][lane] = gid[d0 + lane];
  float bx = bvec[lane * 2], by = bvec[lane * 2 + 1];
  float cx = cvec ? cvec[lane * 2] : 0.f;
  float cy = cvec ? cvec[lane * 2 + 1] : 0.f;
  __syncthreads();
  int s0 = __builtin_amdgcn_readfirstlane(ls_rp[wave][0]);
  int e0 = __builtin_amdgcn_readfirstlane(ls_rp[wave][16]);
  u32 vob = (u32)(lane * 2);
  float ax = 0.f, ay = 0.f, wsum = 0.f;
  int ld = 0;
  int nb = __builtin_amdgcn_readfirstlane(ls_rp[wave][1]);

  auto flush = [&]() {
    float rx = fmaxf(ax + cx * wsum + bx, 0.f);
    float ry = fmaxf(ay + cy * wsum + by, 0.f);
    u32 pk2 = ((u32)f2bf(ry) << 16) | (u32)f2bf(rx);
    *(u32*)&otile[wave][ld * 128 + lane * 2] = pk2;   // LDS only — no vmem
    ax = 0.f;
    ay = 0.f;
    wsum = 0.f;
    ++ld;
    nb = __builtin_amdgcn_readfirstlane(ls_rp[wave][ld < 16 ? ld + 1 : 16]);
  };

  if (s0 < e0) {
    int e0m1 = e0 - 1;
    u32 pkA[AB2], pkB[AB2];
    u32 vaA[AB2], vaB[AB2];
    float wvA[AB2], wvB[AB2];

#define LOADPK1(PK, J0)                               \
  _Pragma("unroll") for (int k = 0; k < AB2; ++k) {   \
    int jc = (J0) + k;                                \
    jc = jc < e0 ? jc : e0m1;                         \
    PK[k] = csrP[jc];                                 \
  }
#define ISSUE1(VA, WV, PK)                            \
  _Pragma("unroll") for (int k = 0; k < AB2; ++k) {   \
    u32 p = PK[k];                                    \
    u32 off = ((p & 0x1FFFFu) << 7) | vob;            \
    VA[k] = *(const u16*)(z + off);                   \
    WV[k] = (float)(p >> 17) * WDQ;                   \
  }
#define CONS1(VA, WV, J0)                             \
  _Pragma("unroll") for (int k = 0; k < AB2; ++k) {   \
    int j = (J0) + k;                                 \
    if (j < e0) {                                     \
      while (j >= nb) flush();                        \
      float w = WV[k];                                \
      wsum += w;                                      \
      f32x2 d = __builtin_amdgcn_cvt_pk_f32_fp8((int)VA[k], false); \
      ax += d.x * w;                                  \
      ay += d.y * w;                                  \
    }                                                 \
  }

    LOADPK1(pkA, s0)
    ISSUE1(vaA, wvA, pkA)
    LOADPK1(pkA, s0 + AB2)
    int jb = s0;
    while (true) {
      LOADPK1(pkB, jb + 2 * AB2)
      if (jb + AB2 < e0) { ISSUE1(vaB, wvB, pkA) }
      CONS1(vaA, wvA, jb)
      if (jb + AB2 >= e0) break;
      LOADPK1(pkA, jb + 3 * AB2)
      if (jb + 2 * AB2 < e0) { ISSUE1(vaA, wvA, pkB) }
      CONS1(vaB, wvB, jb + AB2)
      if (jb + 2 * AB2 >= e0) break;
      jb += 2 * AB2;
    }
#undef LOADPK1
#undef ISSUE1
#undef CONS1
  }
  while (ld < 16) flush();

  // epilogue 1: coalesced copy of the wave's tile -> out
  {
    const u16* srcl = &otile[wave][0];
    u16* dstg = out + (size_t)d0 * 128;
#pragma unroll
    for (int i = 0; i < 4; ++i) {
      uint4 v = *(const uint4*)(srcl + i * 512 + lane * 8);
      *(uint4*)(dstg + i * 512 + lane * 8) = v;
    }
  }
  // epilogue 2: per-graph pooling from the tile (atomics out of the hot loop)
  {
    float runx = 0.f, runy = 0.f;
    int curg = __builtin_amdgcn_readfirstlane(ls_gid[wave][0]);
    for (int r = 0; r < 16; ++r) {
      u32 v = *(const u32*)&otile[wave][r * 128 + lane * 2];
      float rx = blo(v), ry = bhi(v);
      int gn = __builtin_amdgcn_readfirstlane(ls_gid[wave][r]);
      if (gn != curg) {
        atomicAdd(&hg[curg * 384 + coloff + lane * 2], runx);
        atomicAdd(&hg[curg * 384 + coloff + lane * 2 + 1], runy);
        runx = 0.f;
        runy = 0.f;
        curg = gn;
      }
      runx += rx;
      runy += ry;
    }
    atomicAdd(&hg[curg * 384 + coloff + lane * 2], runx);
    atomicAdd(&hg[curg * 384 + coloff + lane * 2 + 1], runy);
  }
}

// ---------------- classifier ----------------
__global__ void classifier(const float* __restrict__ hg, const float* __restrict__ w1,
                           const float* __restrict__ b1, const float* __restrict__ w2,
                           const float* __restrict__ b2, float* __restrict__ out) {
  __shared__ float sh_hg[16 * 384];
  __shared__ float sh_z[16 * 128];
  int t = threadIdx.x;
  for (int u = t; u < 16 * 384; u += 256) sh_hg[u] = hg[u];
  __syncthreads();
  for (int u = 0; u < 8; ++u) {
    int idx = t + u * 256;
    int b = idx >> 7, o = idx & 127;
    float a = b1[o];
    for (int i = 0; i < 384; ++i) a += sh_hg[b * 384 + i] * w1[o * 384 + i];
    sh_z[b * 128 + o] = a;
  }
  __syncthreads();
  if (t < 80) {
    int b = t / 5, c = t % 5;
    float a = b2[c];
    for (int i = 0; i < 128; ++i) a += sh_z[b * 128 + i] * w2[c * 128 + i];
    out[b * 5 + c] = a;
  }
}

extern "C" void kernel_launch(void* const* d_in, const int* in_sizes, int n_in,
                              void* d_out, int out_size, void* d_ws, size_t ws_size,
                              hipStream_t stream) {
  const float* h = (const float*)d_in[0];
  const float* edge_w = (const float*)d_in[1];
  const int* src = (const int*)d_in[2];
  const int* dst = (const int*)d_in[3];
  const int* gid = (const int*)d_in[4];
  const float* c1w = (const float*)d_in[6];
  const float* c1b = (const float*)d_in[7];
  const float* c2w = (const float*)d_in[8];
  const float* c2b = (const float*)d_in[9];
  const float* c3w = (const float*)d_in[10];
  const float* c3b = (const float*)d_in[11];
  const float* pw = (const float*)d_in[12];
  const float* pb = (const float*)d_in[13];
  const float* g11w = (const float*)d_in[14];
  const float* g11b = (const float*)d_in[15];
  const float* g12w = (const float*)d_in[16];
  const float* g12b = (const float*)d_in[17];
  const float* g13w = (const float*)d_in[18];
  const float* g13b = (const float*)d_in[19];
  const float* g2w = (const float*)d_in[20];
  const float* g2b = (const float*)d_in[21];
  const float* g3w = (const float*)d_in[22];
  const float* g3b = (const float*)d_in[23];
  const float* g4w = (const float*)d_in[24];
  const float* g4b = (const float*)d_in[25];
  const float* bng = (const float*)d_in[26];
  const float* bnb = (const float*)d_in[27];
  const float* cl1w = (const float*)d_in[28];
  const float* cl1b = (const float*)d_in[29];
  const float* cl2w = (const float*)d_in[30];
  const float* cl2b = (const float*)d_in[31];

  char* ws = (char*)d_ws;
  u16* H16 = (u16*)(ws + H16_OFF);
  u16* A = (u16*)(ws + A_OFF);
  u16* B = (u16*)(ws + B_OFF);
  u16* C = (u16*)(ws + C_OFF);
  unsigned char* F12 = (unsigned char*)(ws + H16_OFF);  // fp8 [N][256], 32 MB
  unsigned char* F3 = (unsigned char*)(ws + Z_OFF);     // fp8 [N][128], 16 MB
  unsigned char* FS2 = (unsigned char*)(ws + H16_OFF);  // stage-2 fp8 [N][128]
  u16* re = (u16*)(ws + RE_OFF);  // edge ranks (dead before F3 written)
  u16* P = (u16*)(ws + A_OFF);    // bf16 press output (A's t1 dead by then)
  u32* csrP = (u32*)(ws + CSR_OFF);
  int* rp = (int*)(ws + RP_OFF);
  int* deg = (int*)(ws + DEG_OFF);
  int* bs = (int*)(ws + BS_OFF);
  float* sums = (float*)(ws + SUMS_OFF);
  float* hg = (float*)(ws + HG_OFF);
  u16* wT16 = (u16*)(ws + WT16_OFF);
  u16* wP16 = (u16*)(ws + WP16_OFF);
  float* cp = (float*)(ws + CP_OFF);
  float* sv = (float*)(ws + SV_OFF);
  float* shv = (float*)(ws + SHV_OFF);
  float* outp = (float*)d_out;

  zerok<<<512, 256, 0, stream>>>(deg, sums, hg);
  h2bf_deg<<<8192, 256, 0, stream>>>(h, H16, dst, deg, re);
  prep_wT16<<<1728, 256, 0, stream>>>(c1w, c2w, c3w, wT16);
  wprep16<<<64, 256, 0, stream>>>(g3w, (const float*)nullptr, wP16 + 4 * 17408);
  wprep16<<<64, 256, 0, stream>>>(g4w, (const float*)nullptr, wP16 + 5 * 17408);

  mfma_gemm<3, 1, 0><<<1024, 256, 0, stream>>>(H16, wT16 + 0 * 52224, A, 0);
  mfma_gemm<3, 2, 0><<<1024, 256, 0, stream>>>(H16, wT16 + 1 * 52224, B, 0);
  mfma_gemm<3, 3, 0><<<1024, 256, 0, stream>>>(H16, wT16 + 2 * 52224, C, 0);
  combine<<<4096, 256, 0, stream>>>(A, B, C, c1b, c2b, c3b, sums);

  // CSR placement (deg+rank already computed in h2bf_deg)
  scan1<<<512, 256, 0, stream>>>(deg, rp, bs);
  scan2<<<1, 512, 0, stream>>>(bs);
  scan3<<<512, 256, 0, stream>>>(rp, bs);
  csr_fill2<<<8192, 256, 0, stream>>>(src, dst, edge_w, rp, re, csrP);

  bnparam<<<3, 128, 0, stream>>>(sums, bng, bnb, sv, shv, 0);
  wprep16<<<64, 256, 0, stream>>>(g11w, sv + 0 * 128, wP16 + 0 * 17408);
  cprep<<<1, 128, 0, stream>>>(g11w, shv + 0 * 128, cp + 0 * 128);
  wprep16<<<64, 256, 0, stream>>>(g12w, sv + 1 * 128, wP16 + 1 * 17408);
  cprep<<<1, 128, 0, stream>>>(g12w, shv + 1 * 128, cp + 1 * 128);
  wprep16<<<64, 256, 0, stream>>>(g13w, sv + 2 * 128, wP16 + 2 * 17408);
  cprep<<<1, 128, 0, stream>>>(g13w, shv + 2 * 128, cp + 2 * 128);

  // stage 1: z1,z2 -> F12 pair-interleaved (stride 256, ch offsets 0/128);
  // z3 -> F3 (stride 128). Then fused agg+press -> P + BN stats(t3).
  mfma_gemm<1, 0, 1><<<1024, 256, 0, stream>>>(A, wP16 + 0 * 17408, (u16*)F12, 256);
  mfma_gemm<1, 0, 1><<<1024, 256, 0, stream>>>(B, wP16 + 1 * 17408, (u16*)(F12 + 128), 256);
  mfma_gemm<1, 0, 1><<<1024, 256, 0, stream>>>(C, wP16 + 2 * 17408, (u16*)F3, 128);
  agg3_press<<<2048, 256, 0, stream>>>(F12, F3, csrP, rp, cp, g11b, g12b,
                                       g13b, pw, pb, P, sums);

  bnparam<<<1, 128, 0, stream>>>(sums, bng, bnb, sv, shv, 3);
  wprep16<<<64, 256, 0, stream>>>(g2w, sv + 3 * 128, wP16 + 3 * 17408);
  cprep<<<1, 128, 0, stream>>>(g2w, shv + 3 * 128, cp + 3 * 128);

  // stage 2 chain: GEMM -> fp8 FS2 (H16 region, F12 dead), gather -> bf16 rows
  mfma_gemm<1, 0, 1><<<1024, 256, 0, stream>>>(P, wP16 + 3 * 17408, (u16*)FS2, 128);  // y2
  agg2<<<2048, 256, 0, stream>>>(FS2, csrP, rp, cp + 3 * 128, g2b, B, gid, hg, 0);
  mfma_gemm<1, 0, 1><<<1024, 256, 0, stream>>>(B, wP16 + 4 * 17408, (u16*)FS2, 128);  // y3
  agg2<<<2048, 256, 0, stream>>>(FS2, csrP, rp, (const float*)nullptr, g3b, C, gid, hg, 128);
  mfma_gemm<1, 0, 1><<<1024, 256, 0, stream>>>(C, wP16 + 5 * 17408, (u16*)FS2, 128);  // y4
  agg2<<<2048, 256, 0, stream>>>(FS2, csrP, rp, (const float*)nullptr, g4b, A, gid, hg, 256);

  classifier<<<1, 256, 0, stream>>>(hg, cl1w, cl1b, cl2w, cl2b, outp);
}